// Round 6
// baseline (316.054 us; speedup 1.0000x reference)
//
#include <hip/hip_runtime.h>
#include <hip/hip_bf16.h>
#include <math.h>

#define B_ 32
#define C_ 2048
#define HW_ 576          // 24*24
#define P_ 4
#define HID_ 128         // C/RED
#define J_ 8192          // C*P
#define NCHUNK_ 8        // c-chunks of 256 channels
#define NSLOT_ 8         // one slot per chunk (in-block group reduction)

// ---------------- K1: pool (blocks 0..16383) + transpose of fc2_w (blocks 16384..17407) ----
// pool: one wave per (b,c) row of 576 floats (144 float4), 4 waves/block.
// transpose: w[j,k] (8192x128) -> wt[k,j] (128x8192) via 32x32 LDS tiles.
__global__ void pool_trans_kernel(const float* __restrict__ x, float* __restrict__ pooled,
                                  const float* __restrict__ fc2_w, float* __restrict__ wt) {
    int bid = blockIdx.x;
    int tid = threadIdx.x;
    if (bid < 16384) {
        int gwave = bid * 4 + (tid >> 6);              // [0, 65536)
        int lane  = tid & 63;
        const float4* xp4 = (const float4*)(x + (size_t)gwave * HW_);
        float s = 0.f;
        for (int i = lane; i < HW_ / 4; i += 64) {     // 144 float4
            float4 v = xp4[i];
            s += v.x + v.y + v.z + v.w;
        }
        #pragma unroll
        for (int off = 32; off > 0; off >>= 1) s += __shfl_down(s, off, 64);
        if (lane == 0) pooled[gwave] = s * (1.0f / (float)HW_);
    } else {
        __shared__ float tile[32][33];
        int bid2 = bid - 16384;
        int kt = bid2 & 3;                             // 0..3
        int jt = bid2 >> 2;                            // 0..255
        int tx = tid & 31;
        int ty = tid >> 5;                             // 0..7
        #pragma unroll
        for (int i = 0; i < 32; i += 8)
            tile[ty + i][tx] = fc2_w[(size_t)(jt * 32 + ty + i) * HID_ + kt * 32 + tx];
        __syncthreads();
        #pragma unroll
        for (int i = 0; i < 32; i += 8)
            wt[(size_t)(kt * 32 + ty + i) * J_ + jt * 32 + tx] = tile[tx][ty + i];
    }
}

// ---------------- K2: fc1: hidden[b,j] = silu(pooled[b,:]·fc1_w[j,:] + b1[j]) -----------
// one wave per output (32*128 = 4096 outputs), 4 waves/block -> 1024 blocks
__global__ void fc1_kernel(const float* __restrict__ pooled, const float* __restrict__ fc1_w,
                           const float* __restrict__ fc1_b, float* __restrict__ hidden) {
    int o    = blockIdx.x * 4 + (threadIdx.x >> 6);    // [0, 4096)
    int lane = threadIdx.x & 63;
    int b = o >> 7;
    int j = o & 127;
    const float* pr = pooled + (size_t)b * C_;
    const float* wr = fc1_w + (size_t)j * C_;
    float s = 0.f;
    for (int k = lane; k < C_; k += 64) s += pr[k] * wr[k];
    #pragma unroll
    for (int off = 32; off > 0; off >>= 1) s += __shfl_down(s, off, 64);
    if (lane == 0) {
        float z = s + fc1_b[j];
        hidden[o] = z / (1.0f + expf(-z));             // silu
    }
}

// ---------------- K3: fc2 + conv_b partial reduction + einsum-counter init ----------------
// grid (b=32 x jc=8) = 256 blocks, 256 threads; thread owns 4 consecutive j's.
// Also writes bias_part[b*8+jc] = sum_{j in chunk} conv_b[j&2047] * dw[b,j]
// and block (b, jc==0) zeroes cnt[b] for K4's last-block detection
// (kernel boundary makes the store visible to K4).
__global__ void fc2_kernel(const float* __restrict__ hidden, const float* __restrict__ wt,
                           const float* __restrict__ bias, const float* __restrict__ conv_b,
                           float* __restrict__ dw, float* __restrict__ bias_part,
                           unsigned int* __restrict__ cnt) {
    int b  = blockIdx.x >> 3;
    int jc = blockIdx.x & 7;
    int tid = threadIdx.x;

    if (jc == 0 && tid == 0) cnt[b] = 0u;

    __shared__ float h[HID_];
    if (tid < HID_) h[tid] = hidden[(size_t)b * HID_ + tid];
    __syncthreads();

    int j4 = jc * 256 + tid;                 // float4 column index: j = 4*j4
    const float4* wt4 = (const float4*)wt;   // [k][J_/4]
    float4 acc = {0.f, 0.f, 0.f, 0.f};
    #pragma unroll 8
    for (int k = 0; k < HID_; ++k) {
        float4 wv = wt4[(size_t)k * (J_ / 4) + j4];
        float hk = h[k];
        acc.x += wv.x * hk;
        acc.y += wv.y * hk;
        acc.z += wv.z * hk;
        acc.w += wv.w * hk;
    }
    const float4* b4 = (const float4*)bias;
    float4 bb = b4[j4];
    acc.x += bb.x; acc.y += bb.y; acc.z += bb.z; acc.w += bb.w;
    ((float4*)(dw + (size_t)b * J_))[j4] = acc;

    // conv_b · dw partial for this block's p
    int c = (4 * j4) & (C_ - 1);             // multiple of 4
    float4 cb = *(const float4*)(conv_b + c);
    float local = cb.x * acc.x + cb.y * acc.y + cb.z * acc.z + cb.w * acc.w;
    #pragma unroll
    for (int off = 32; off > 0; off >>= 1) local += __shfl_down(local, off, 64);
    __shared__ float wsum[4];
    if ((tid & 63) == 0) wsum[tid >> 6] = local;
    __syncthreads();
    if (tid == 0) bias_part[(b << 3) + jc] = wsum[0] + wsum[1] + wsum[2] + wsum[3];
}

// ---------------- K4: einsum partials + last-block-per-b softmax ----------------
// grid (b=32, chunk=8); 256 channels per chunk; 576 threads in 4 groups of 144.
// Group g handles channels c0+g+4k; groups cover the same hw range, reduced in LDS.
// The last block of each b (device-scope counter) reduces the 8 slots + bias
// and writes the softmax output for that b.
__global__ void einsum_softmax_kernel(const float* __restrict__ x, const float* __restrict__ conv_w,
                                      const float* __restrict__ dw, float* __restrict__ part,
                                      const float* __restrict__ bias_part,
                                      unsigned int* __restrict__ cnt, float* __restrict__ out) {
    int b     = blockIdx.x;
    int chunk = blockIdx.y;
    int c0    = chunk * 256;
    int tid   = threadIdx.x;                           // [0, 576)

    __shared__ float4 m4[256];                         // m4[c] = {cw*dw[p=0..3]}
    __shared__ float4 red[P_ * HW_];                   // red[p*576 + tid]  (36 KB)
    __shared__ unsigned int old_s;
    if (tid < 256) {
        float cw = conv_w[c0 + tid];
        const float* dr = dw + (size_t)b * (P_ * C_) + c0 + tid;
        float4 v;
        v.x = cw * dr[0 * C_];
        v.y = cw * dr[1 * C_];
        v.z = cw * dr[2 * C_];
        v.w = cw * dr[3 * C_];
        m4[tid] = v;
    }
    __syncthreads();

    int g = tid / 144;                                 // 0..3
    int i = tid - g * 144;                             // 0..143  (float4 index in hw)

    float4 a0 = {0,0,0,0}, a1 = {0,0,0,0}, a2 = {0,0,0,0}, a3 = {0,0,0,0};
    const float* xb = x + ((size_t)b * C_ + c0) * HW_;
    #pragma unroll 4
    for (int k = 0; k < 64; ++k) {
        int c = g + 4 * k;
        float4 v = ((const float4*)(xb + (size_t)c * HW_))[i];
        float4 m = m4[c];
        a0.x += v.x * m.x; a0.y += v.y * m.x; a0.z += v.z * m.x; a0.w += v.w * m.x;
        a1.x += v.x * m.y; a1.y += v.y * m.y; a1.z += v.z * m.y; a1.w += v.w * m.y;
        a2.x += v.x * m.z; a2.y += v.y * m.z; a2.z += v.z * m.z; a2.w += v.w * m.z;
        a3.x += v.x * m.w; a3.y += v.y * m.w; a3.z += v.z * m.w; a3.w += v.w * m.w;
    }
    red[0 * HW_ + tid] = a0;
    red[1 * HW_ + tid] = a1;
    red[2 * HW_ + tid] = a2;
    red[3 * HW_ + tid] = a3;
    __syncthreads();

    if (g == 0) {                                      // tid == i in [0,144)
        float4* pp = (float4*)(part + (((size_t)b * NSLOT_ + chunk) * P_) * HW_);
        #pragma unroll
        for (int p = 0; p < P_; ++p) {
            float4 s  = red[p * HW_ + i];
            float4 s1 = red[p * HW_ + 144 + i];
            float4 s2 = red[p * HW_ + 288 + i];
            float4 s3 = red[p * HW_ + 432 + i];
            s.x += s1.x + s2.x + s3.x;
            s.y += s1.y + s2.y + s3.y;
            s.z += s1.z + s2.z + s3.z;
            s.w += s1.w + s2.w + s3.w;
            pp[p * (HW_ / 4) + i] = s;
        }
    }

    // release our part writes, then count this block done for batch b
    __threadfence();
    __syncthreads();
    if (tid == 0) old_s = atomicAdd(&cnt[b], 1u);
    __syncthreads();
    if (old_s != NCHUNK_ - 1) return;                  // not the last block of this b

    // last block: acquire, reduce 8 slots + bias, softmax over p, write out
    __threadfence();
    int hw = tid;                                      // [0, 576)
    const float* bp = bias_part + b * 8;
    float v0 = bp[0] + bp[1];
    float v1 = bp[2] + bp[3];
    float v2 = bp[4] + bp[5];
    float v3 = bp[6] + bp[7];
    const float* pb = part + ((size_t)b * NSLOT_ * P_) * HW_ + hw;
    #pragma unroll
    for (int s = 0; s < NSLOT_; ++s) {
        const float* ps = pb + (size_t)s * P_ * HW_;
        v0 += ps[0 * HW_];
        v1 += ps[1 * HW_];
        v2 += ps[2 * HW_];
        v3 += ps[3 * HW_];
    }
    float mx = fmaxf(fmaxf(v0, v1), fmaxf(v2, v3));
    float e0 = expf(v0 - mx), e1 = expf(v1 - mx), e2 = expf(v2 - mx), e3 = expf(v3 - mx);
    float inv = 1.0f / (e0 + e1 + e2 + e3);
    float* op = out + ((size_t)b * P_) * HW_ + hw;
    op[0 * HW_] = e0 * inv;
    op[1 * HW_] = e1 * inv;
    op[2 * HW_] = e2 * inv;
    op[3 * HW_] = e3 * inv;
}

extern "C" void kernel_launch(void* const* d_in, const int* in_sizes, int n_in,
                              void* d_out, int out_size, void* d_ws, size_t ws_size,
                              hipStream_t stream) {
    const float* x      = (const float*)d_in[0];
    const float* fc1_w  = (const float*)d_in[1];
    const float* fc1_b  = (const float*)d_in[2];
    const float* fc2_w  = (const float*)d_in[3];
    const float* fc2_b  = (const float*)d_in[4];
    const float* conv_w = (const float*)d_in[5];
    const float* conv_b = (const float*)d_in[6];
    float* out = (float*)d_out;

    // workspace layout (floats)
    float* ws        = (float*)d_ws;
    float* pooled    = ws;                      // 32*2048       = 65536
    float* hidden    = pooled + 65536;          // 32*128        = 4096
    float* dw        = hidden + 4096;           // 32*8192       = 262144
    float* bias_part = dw + 262144;             // 32*8          = 256
    float* part      = bias_part + 256;         // 32*8*4*576    = 589824 (2.36 MB)
    float* wt        = part + 589824;           // 128*8192      = 1048576 (4 MB)
    unsigned int* cnt = (unsigned int*)(wt + 1048576);  // 32 counters

    pool_trans_kernel<<<17408, 256, 0, stream>>>(x, pooled, fc2_w, wt);
    fc1_kernel<<<1024, 256, 0, stream>>>(pooled, fc1_w, fc1_b, hidden);
    fc2_kernel<<<256, 256, 0, stream>>>(hidden, wt, fc2_b, conv_b, dw, bias_part, cnt);
    einsum_softmax_kernel<<<dim3(B_, NCHUNK_), 576, 0, stream>>>(x, conv_w, dw, part,
                                                                 bias_part, cnt, out);
}

// Round 7
// 268.152 us; speedup vs baseline: 1.1786x; 1.1786x over previous
//
#include <hip/hip_runtime.h>
#include <hip/hip_bf16.h>
#include <math.h>

#define B_ 32
#define C_ 2048
#define HW_ 576          // 24*24
#define P_ 4
#define HID_ 128         // C/RED
#define J_ 8192          // C*P
#define NCHUNK_ 8        // c-chunks of 256 channels
#define NSLOT_ 8         // one slot per chunk (in-block group reduction)

// ---------------- K1: pool (blocks 0..16383) + transpose of fc2_w (blocks 16384..17407) ----
// pool: one wave per (b,c) row of 576 floats (144 float4), 4 waves/block.
// transpose: w[j,k] (8192x128) -> wt[k,j] (128x8192) via 32x32 LDS tiles.
__global__ void pool_trans_kernel(const float* __restrict__ x, float* __restrict__ pooled,
                                  const float* __restrict__ fc2_w, float* __restrict__ wt) {
    int bid = blockIdx.x;
    int tid = threadIdx.x;
    if (bid < 16384) {
        int gwave = bid * 4 + (tid >> 6);              // [0, 65536)
        int lane  = tid & 63;
        const float4* xp4 = (const float4*)(x + (size_t)gwave * HW_);
        float s = 0.f;
        for (int i = lane; i < HW_ / 4; i += 64) {     // 144 float4
            float4 v = xp4[i];
            s += v.x + v.y + v.z + v.w;
        }
        #pragma unroll
        for (int off = 32; off > 0; off >>= 1) s += __shfl_down(s, off, 64);
        if (lane == 0) pooled[gwave] = s * (1.0f / (float)HW_);
    } else {
        __shared__ float tile[32][33];
        int bid2 = bid - 16384;
        int kt = bid2 & 3;                             // 0..3
        int jt = bid2 >> 2;                            // 0..255
        int tx = tid & 31;
        int ty = tid >> 5;                             // 0..7
        #pragma unroll
        for (int i = 0; i < 32; i += 8)
            tile[ty + i][tx] = fc2_w[(size_t)(jt * 32 + ty + i) * HID_ + kt * 32 + tx];
        __syncthreads();
        #pragma unroll
        for (int i = 0; i < 32; i += 8)
            wt[(size_t)(kt * 32 + ty + i) * J_ + jt * 32 + tx] = tile[tx][ty + i];
    }
}

// ---------------- K2: fc1: hidden[b,j] = silu(pooled[b,:]·fc1_w[j,:] + b1[j]) -----------
// one wave per output (32*128 = 4096 outputs), 4 waves/block -> 1024 blocks
__global__ void fc1_kernel(const float* __restrict__ pooled, const float* __restrict__ fc1_w,
                           const float* __restrict__ fc1_b, float* __restrict__ hidden) {
    int o    = blockIdx.x * 4 + (threadIdx.x >> 6);    // [0, 4096)
    int lane = threadIdx.x & 63;
    int b = o >> 7;
    int j = o & 127;
    const float* pr = pooled + (size_t)b * C_;
    const float* wr = fc1_w + (size_t)j * C_;
    float s = 0.f;
    for (int k = lane; k < C_; k += 64) s += pr[k] * wr[k];
    #pragma unroll
    for (int off = 32; off > 0; off >>= 1) s += __shfl_down(s, off, 64);
    if (lane == 0) {
        float z = s + fc1_b[j];
        hidden[o] = z / (1.0f + expf(-z));             // silu
    }
}

// ---------------- K3: fc2 + conv_b partial reduction ----------------
// grid (b=32 x jc=8) = 256 blocks, 256 threads; thread owns 4 consecutive j's.
// Also writes bias_part[b*8+jc] = sum_{j in chunk} conv_b[j&2047] * dw[b,j]
// (each jc chunk lies within a single p, so this is a partial of bias_c[b,p]).
__global__ void fc2_kernel(const float* __restrict__ hidden, const float* __restrict__ wt,
                           const float* __restrict__ bias, const float* __restrict__ conv_b,
                           float* __restrict__ dw, float* __restrict__ bias_part) {
    int b  = blockIdx.x >> 3;
    int jc = blockIdx.x & 7;
    int tid = threadIdx.x;

    __shared__ float h[HID_];
    if (tid < HID_) h[tid] = hidden[(size_t)b * HID_ + tid];
    __syncthreads();

    int j4 = jc * 256 + tid;                 // float4 column index: j = 4*j4
    const float4* wt4 = (const float4*)wt;   // [k][J_/4]
    float4 acc = {0.f, 0.f, 0.f, 0.f};
    #pragma unroll 8
    for (int k = 0; k < HID_; ++k) {
        float4 wv = wt4[(size_t)k * (J_ / 4) + j4];
        float hk = h[k];
        acc.x += wv.x * hk;
        acc.y += wv.y * hk;
        acc.z += wv.z * hk;
        acc.w += wv.w * hk;
    }
    const float4* b4 = (const float4*)bias;
    float4 bb = b4[j4];
    acc.x += bb.x; acc.y += bb.y; acc.z += bb.z; acc.w += bb.w;
    ((float4*)(dw + (size_t)b * J_))[j4] = acc;

    // conv_b · dw partial for this block's p
    int c = (4 * j4) & (C_ - 1);             // multiple of 4
    float4 cb = *(const float4*)(conv_b + c);
    float local = cb.x * acc.x + cb.y * acc.y + cb.z * acc.z + cb.w * acc.w;
    #pragma unroll
    for (int off = 32; off > 0; off >>= 1) local += __shfl_down(local, off, 64);
    __shared__ float wsum[4];
    if ((tid & 63) == 0) wsum[tid >> 6] = local;
    __syncthreads();
    if (tid == 0) bias_part[(b << 3) + jc] = wsum[0] + wsum[1] + wsum[2] + wsum[3];
}

// ---------------- K4: einsum partials (one slot per chunk via in-block reduction) --------
// grid (b=32, chunk=8); 256 channels per chunk; 576 threads in 4 groups of 144.
// Group g handles channels c0+g+4k; all groups cover the same hw range, reduced in LDS.
__global__ void einsum_kernel(const float* __restrict__ x, const float* __restrict__ conv_w,
                              const float* __restrict__ dw, float* __restrict__ part) {
    int b     = blockIdx.x;
    int chunk = blockIdx.y;
    int c0    = chunk * 256;
    int tid   = threadIdx.x;                           // [0, 576)

    __shared__ float4 m4[256];                         // m4[c] = {cw*dw[p=0..3]}
    __shared__ float4 red[P_ * HW_];                   // red[p*576 + tid]  (36 KB)
    if (tid < 256) {
        float cw = conv_w[c0 + tid];
        const float* dr = dw + (size_t)b * (P_ * C_) + c0 + tid;
        float4 v;
        v.x = cw * dr[0 * C_];
        v.y = cw * dr[1 * C_];
        v.z = cw * dr[2 * C_];
        v.w = cw * dr[3 * C_];
        m4[tid] = v;
    }
    __syncthreads();

    int g = tid / 144;                                 // 0..3
    int i = tid - g * 144;                             // 0..143  (float4 index in hw)

    float4 a0 = {0,0,0,0}, a1 = {0,0,0,0}, a2 = {0,0,0,0}, a3 = {0,0,0,0};
    const float* xb = x + ((size_t)b * C_ + c0) * HW_;
    #pragma unroll 4
    for (int k = 0; k < 64; ++k) {
        int c = g + 4 * k;
        float4 v = ((const float4*)(xb + (size_t)c * HW_))[i];
        float4 m = m4[c];
        a0.x += v.x * m.x; a0.y += v.y * m.x; a0.z += v.z * m.x; a0.w += v.w * m.x;
        a1.x += v.x * m.y; a1.y += v.y * m.y; a1.z += v.z * m.y; a1.w += v.w * m.y;
        a2.x += v.x * m.z; a2.y += v.y * m.z; a2.z += v.z * m.z; a2.w += v.w * m.z;
        a3.x += v.x * m.w; a3.y += v.y * m.w; a3.z += v.z * m.w; a3.w += v.w * m.w;
    }
    red[0 * HW_ + tid] = a0;
    red[1 * HW_ + tid] = a1;
    red[2 * HW_ + tid] = a2;
    red[3 * HW_ + tid] = a3;
    __syncthreads();

    if (g == 0) {                                      // tid == i in [0,144)
        float4* pp = (float4*)(part + (((size_t)b * NSLOT_ + chunk) * P_) * HW_);
        #pragma unroll
        for (int p = 0; p < P_; ++p) {
            float4 s  = red[p * HW_ + i];
            float4 s1 = red[p * HW_ + 144 + i];
            float4 s2 = red[p * HW_ + 288 + i];
            float4 s3 = red[p * HW_ + 432 + i];
            s.x += s1.x + s2.x + s3.x;
            s.y += s1.y + s2.y + s3.y;
            s.z += s1.z + s2.z + s3.z;
            s.w += s1.w + s2.w + s3.w;
            pp[p * (HW_ / 4) + i] = s;
        }
    }
}

// ---------------- K5: reduce slots + bias + softmax over p ----------------
// thread per (b,hw): 18432 threads = 72 blocks * 256
__global__ void softmax_kernel(const float* __restrict__ part, const float* __restrict__ bias_part,
                               float* __restrict__ out) {
    int idx = blockIdx.x * 256 + threadIdx.x;          // [0, 18432)
    int b  = idx / HW_;
    int hw = idx - b * HW_;
    const float* bp = bias_part + b * 8;
    float v0 = bp[0] + bp[1];
    float v1 = bp[2] + bp[3];
    float v2 = bp[4] + bp[5];
    float v3 = bp[6] + bp[7];
    const float* pb = part + ((size_t)b * NSLOT_ * P_) * HW_ + hw;
    #pragma unroll
    for (int s = 0; s < NSLOT_; ++s) {
        const float* ps = pb + (size_t)s * P_ * HW_;
        v0 += ps[0 * HW_];
        v1 += ps[1 * HW_];
        v2 += ps[2 * HW_];
        v3 += ps[3 * HW_];
    }
    float mx = fmaxf(fmaxf(v0, v1), fmaxf(v2, v3));
    float e0 = expf(v0 - mx), e1 = expf(v1 - mx), e2 = expf(v2 - mx), e3 = expf(v3 - mx);
    float inv = 1.0f / (e0 + e1 + e2 + e3);
    float* op = out + ((size_t)b * P_) * HW_ + hw;
    op[0 * HW_] = e0 * inv;
    op[1 * HW_] = e1 * inv;
    op[2 * HW_] = e2 * inv;
    op[3 * HW_] = e3 * inv;
}

extern "C" void kernel_launch(void* const* d_in, const int* in_sizes, int n_in,
                              void* d_out, int out_size, void* d_ws, size_t ws_size,
                              hipStream_t stream) {
    const float* x      = (const float*)d_in[0];
    const float* fc1_w  = (const float*)d_in[1];
    const float* fc1_b  = (const float*)d_in[2];
    const float* fc2_w  = (const float*)d_in[3];
    const float* fc2_b  = (const float*)d_in[4];
    const float* conv_w = (const float*)d_in[5];
    const float* conv_b = (const float*)d_in[6];
    float* out = (float*)d_out;

    // workspace layout (floats)
    float* ws        = (float*)d_ws;
    float* pooled    = ws;                      // 32*2048       = 65536
    float* hidden    = pooled + 65536;          // 32*128        = 4096
    float* dw        = hidden + 4096;           // 32*8192       = 262144
    float* bias_part = dw + 262144;             // 32*8          = 256
    float* part      = bias_part + 256;         // 32*8*4*576    = 589824 (2.36 MB)
    float* wt        = part + 589824;           // 128*8192      = 1048576 (4 MB)

    pool_trans_kernel<<<17408, 256, 0, stream>>>(x, pooled, fc2_w, wt);
    fc1_kernel<<<1024, 256, 0, stream>>>(pooled, fc1_w, fc1_b, hidden);
    fc2_kernel<<<256, 256, 0, stream>>>(hidden, wt, fc2_b, conv_b, dw, bias_part);
    einsum_kernel<<<dim3(B_, NCHUNK_), 576, 0, stream>>>(x, conv_w, dw, part);
    softmax_kernel<<<72, 256, 0, stream>>>(part, bias_part, out);
}